// Round 8
// baseline (453.303 us; speedup 1.0000x reference)
//
#include <hip/hip_runtime.h>
#include <math.h>

#define DXY   64
#define NN    4096      // 64*64
#define NB    2
#define CP    65        // LDS complex pitch (bank-spread pad) -- round-8: reverted
                        // to pitch-65; XOR swizzle cost VALU (+8.6%) and traffic
                        // (+80MB/dispatch) for zero occupancy gain.

#define C16 0.9238795325112867f
#define S16 0.3826834323650898f
#define R22 0.7071067811865476f

__device__ __forceinline__ void cmul_ip(float2& a, float wr, float wi) {
    float t = a.x * wr - a.y * wi;
    a.y = a.x * wi + a.y * wr;
    a.x = t;
}

// radix-4 core in place on y[i0..i3]; inv selects +i rotation (conj core, unscaled)
__device__ __forceinline__ void bf4(float2* y, int i0, int i1, int i2, int i3, int inv) {
    float2 a0 = y[i0], a1 = y[i1], a2 = y[i2], a3 = y[i3];
    float t0r = a0.x + a2.x, t0i = a0.y + a2.y;
    float t1r = a0.x - a2.x, t1i = a0.y - a2.y;
    float t2r = a1.x + a3.x, t2i = a1.y + a3.y;
    float dr  = a1.x - a3.x, di  = a1.y - a3.y;
    float t3r, t3i;
    if (inv) { t3r = -di; t3i = dr; } else { t3r = di; t3i = -dr; }
    y[i0] = make_float2(t0r + t2r, t0i + t2i);
    y[i1] = make_float2(t1r + t3r, t1i + t3i);
    y[i2] = make_float2(t0r - t2r, t0i - t2i);
    y[i3] = make_float2(t1r - t3r, t1i - t3i);
}

// 16-pt DIF radix-4 (natural in, base-4 digit-reversed out), constant twiddles
__device__ __forceinline__ void fft16_fwd(float2* y) {
    bf4(y, 0, 4, 8, 12, 0);
    bf4(y, 1, 5, 9, 13, 0);
    cmul_ip(y[5],  C16, -S16); cmul_ip(y[9],  R22, -R22); cmul_ip(y[13],  S16, -C16);
    bf4(y, 2, 6, 10, 14, 0);
    cmul_ip(y[6],  R22, -R22); cmul_ip(y[10], 0.f, -1.f); cmul_ip(y[14], -R22, -R22);
    bf4(y, 3, 7, 11, 15, 0);
    cmul_ip(y[7],  S16, -C16); cmul_ip(y[11], -R22, -R22); cmul_ip(y[15], -C16,  S16);
    bf4(y, 0, 1, 2, 3, 0); bf4(y, 4, 5, 6, 7, 0);
    bf4(y, 8, 9, 10, 11, 0); bf4(y, 12, 13, 14, 15, 0);
}

// exact unscaled inverse of fft16_fwd (consumes its layout), = 16 * IDFT16
__device__ __forceinline__ void fft16_inv(float2* y) {
    bf4(y, 0, 1, 2, 3, 1); bf4(y, 4, 5, 6, 7, 1);
    bf4(y, 8, 9, 10, 11, 1); bf4(y, 12, 13, 14, 15, 1);
    cmul_ip(y[5],  C16,  S16); cmul_ip(y[9],  R22,  R22); cmul_ip(y[13],  S16,  C16);
    cmul_ip(y[6],  R22,  R22); cmul_ip(y[10], 0.f,  1.f); cmul_ip(y[14], -R22,  R22);
    cmul_ip(y[7],  S16,  C16); cmul_ip(y[11], -R22,  R22); cmul_ip(y[15], -C16, -S16);
    bf4(y, 0, 4, 8, 12, 1); bf4(y, 1, 5, 9, 13, 1);
    bf4(y, 2, 6, 10, 14, 1); bf4(y, 3, 7, 11, 15, 1);
}

// Forward 64-pt FFT over 64 lines. Thread (u,k1): cross radix-4 gather (4-way
// broadcast reads) -> in-register 16-pt FFT -> [optional W-mult] -> write own
// segment [16k1..16k1+15]. US = line stride, NS = element stride (complex).
template<int US, int NS, bool FUSEW>
__device__ void fwd_pass(float2* z, const float2* __restrict__ wf, int u, int k1,
                         float c1r, float c1i, float s2, float2 Wb)
{
    const int B = u * US;
    float2 y[16];
    float twr = 1.f, twi = 0.f;
#pragma unroll
    for (int n2 = 0; n2 < 16; ++n2) {
        float2 x0 = z[B + n2 * NS];
        float2 x1 = z[B + (n2 + 16) * NS];
        float2 x2 = z[B + (n2 + 32) * NS];
        float2 x3 = z[B + (n2 + 48) * NS];
        float er  = fmaf(s2, x2.x, x0.x), ei = fmaf(s2, x2.y, x0.y);
        float orr = fmaf(s2, x3.x, x1.x), oi = fmaf(s2, x3.y, x1.y);
        float br = er + c1r * orr - c1i * oi;
        float bi = ei + c1r * oi + c1i * orr;
        y[n2].x = twr * br - twi * bi;
        y[n2].y = twr * bi + twi * br;
        float t = twr * Wb.x - twi * Wb.y;
        twi = twr * Wb.y + twi * Wb.x;
        twr = t;
    }
    fft16_fwd(y);
    if (FUSEW) {
#pragma unroll
        for (int p = 0; p < 16; ++p) {
            float2 wv = wf[(16 * k1 + p) * 64 + u];
            cmul_ip(y[p], wv.x, wv.y);
        }
    }
    __syncthreads();   // all gather reads complete before anyone overwrites
#pragma unroll
    for (int p = 0; p < 16; ++p) z[B + (16 * k1 + p) * NS] = y[p];
    __syncthreads();
}

// Inverse: read own segment -> in-register 16-pt IFFT -> conj cross twiddle ->
// store H -> gather across segments -> conj cross radix-4 -> write natural.
template<int US, int NS>
__device__ void inv_pass(float2* z, int u, int k1,
                         float ci1r, float ci1i, float s2, float2 Wbc)
{
    const int B = u * US;
    float2 y[16];
#pragma unroll
    for (int p = 0; p < 16; ++p) y[p] = z[B + (16 * k1 + p) * NS];
    fft16_inv(y);
    float twr = 1.f, twi = 0.f;
#pragma unroll
    for (int n2 = 0; n2 < 16; ++n2) {
        cmul_ip(y[n2], twr, twi);
        float t = twr * Wbc.x - twi * Wbc.y;
        twi = twr * Wbc.y + twi * Wbc.x;
        twr = t;
    }
#pragma unroll
    for (int n2 = 0; n2 < 16; ++n2) z[B + (16 * k1 + n2) * NS] = y[n2]; // own slots
    __syncthreads();
    float2 xx[16];
#pragma unroll
    for (int n2 = 0; n2 < 16; ++n2) {
        float2 h0 = z[B + n2 * NS];
        float2 h1 = z[B + (n2 + 16) * NS];
        float2 h2 = z[B + (n2 + 32) * NS];
        float2 h3 = z[B + (n2 + 48) * NS];
        float er  = fmaf(s2, h2.x, h0.x), ei = fmaf(s2, h2.y, h0.y);
        float orr = fmaf(s2, h3.x, h1.x), oi = fmaf(s2, h3.y, h1.y);
        xx[n2].x = er + ci1r * orr - ci1i * oi;
        xx[n2].y = ei + ci1r * oi + ci1i * orr;
    }
    __syncthreads();
#pragma unroll
    for (int n2 = 0; n2 < 16; ++n2) z[B + (16 * k1 + n2) * NS] = xx[n2];
    __syncthreads();
}

// Packed per-row-pair conv: rows (2blk, 2blk+1) -> re/im of one complex 64x64
// 2D FFT conv. Optional s[I]*s[K] input scaling (sstd). Optional fused
// normalize from the RAW var accumulator (varp): rstd computed inline via
// rsqrtf -- removes the std_kernel dispatch from the critical path.
// Last-block specials: mean path (K1) or std_out writer (K3).
__global__ __launch_bounds__(256, 4)
void row_conv2_kernel(const float* __restrict__ in, float* __restrict__ out,
                      const float2* __restrict__ wfft_br,
                      const float* __restrict__ sstd,
                      const float* __restrict__ varp,
                      const float* __restrict__ mean_i,
                      float* __restrict__ mean_o,
                      float* __restrict__ std_o)
{
    __shared__ float2 z[64 * CP];
    const int tid = threadIdx.x;

    const float* ip = in;
    float*       op = out;
    const float* sstdp = sstd;
    const float* vpp   = varp;
    int bid = blockIdx.x;
    if ((mean_i || std_o) && bid == (int)gridDim.x - 1) {
        if (std_o) {        // K3 tail block: write std_out from var
#pragma unroll
            for (int i = 0; i < 32; ++i) {
                int p = tid + 256 * i;
                std_o[p] = sqrtf(fmaxf(varp[p], 1e-12f));
            }
            return;
        }
        ip = mean_i; op = mean_o; sstdp = nullptr; vpp = nullptr; bid = 0;
    }

    const int u   = ((tid >> 6) << 4) | (tid & 15);
    const int k1  = (tid >> 4) & 3;
    const float c1r = (k1 == 0) ? 1.f : ((k1 == 2) ? -1.f : 0.f);
    const float c1i = (k1 == 1) ? -1.f : ((k1 == 3) ? 1.f : 0.f);
    const float s2  = (k1 & 1) ? -1.f : 1.f;
    const float ang = -0.09817477042468103f * (float)k1;   // -2π/64 * k1
    const float2 Wb  = make_float2(cosf(ang), sinf(ang));
    const float2 Wbc = make_float2(Wb.x, -Wb.y);
    const float ci1r = c1r, ci1i = -c1i;

    const int row0 = 2 * bid;
    const long long off0 = (long long)row0 * NN, off1 = off0 + NN;
    const int b   = row0 >> 12;
    const int rI0 = row0 & (NN - 1), rI1 = rI0 + 1;
    const float* sb = nullptr;
    float sI0 = 1.f, sI1 = 1.f;
    if (sstdp) { sb = sstdp + (long long)b * NN; sI0 = sb[rI0]; sI1 = sb[rI1]; }

    // batched loads: all global reads in flight before any LDS write
    float4 a4[4], c4[4], s4[4];
#pragma unroll
    for (int i = 0; i < 4; ++i) {
        int p = (tid + 256 * i) * 4;
        a4[i] = *(const float4*)(ip + off0 + p);
        c4[i] = *(const float4*)(ip + off1 + p);
    }
    if (sb) {
#pragma unroll
        for (int i = 0; i < 4; ++i) {
            int p = (tid + 256 * i) * 4;
            s4[i] = *(const float4*)(sb + p);
        }
    }
#pragma unroll
    for (int i = 0; i < 4; ++i) {
        int p = (tid + 256 * i) * 4;
        int r = p >> 6, c = p & 63;
        float4 a = a4[i], cc = c4[i];
        if (sb) {
            float4 s = s4[i];
            a.x *= sI0 * s.x; a.y *= sI0 * s.y; a.z *= sI0 * s.z; a.w *= sI0 * s.w;
            cc.x *= sI1 * s.x; cc.y *= sI1 * s.y; cc.z *= sI1 * s.z; cc.w *= sI1 * s.w;
        }
        float2* zp = z + r * CP + c;
        zp[0] = make_float2(a.x, cc.x);
        zp[1] = make_float2(a.y, cc.y);
        zp[2] = make_float2(a.z, cc.z);
        zp[3] = make_float2(a.w, cc.w);
    }
    __syncthreads();

    fwd_pass<CP, 1, false>(z, nullptr,  u, k1, c1r, c1i, s2, Wb);  // fast axis
    fwd_pass<1, CP, true >(z, wfft_br,  u, k1, c1r, c1i, s2, Wb);  // slow axis + W
    inv_pass<1, CP>(z, u, k1, ci1r, ci1i, s2, Wbc);                // slow axis
    inv_pass<CP, 1>(z, u, k1, ci1r, ci1i, s2, Wbc);                // fast axis

    const float scale = 1.0f / 4096.0f;
    float s0 = scale, s1 = scale;
    const float* vb = nullptr;
    if (vpp) {
        vb = vpp + (long long)b * NN;
        s0 *= rsqrtf(fmaxf(vb[rI0], 1e-12f));
        s1 *= rsqrtf(fmaxf(vb[rI1], 1e-12f));
    }
#pragma unroll
    for (int i = 0; i < 4; ++i) {
        int idx = tid + 256 * i;
        int p = idx * 4;
        int r = p >> 6, c = p & 63;
        const float2* zp = z + r * CP + c;
        float4 a, cc;
        a.x = zp[0].x; a.y = zp[1].x; a.z = zp[2].x; a.w = zp[3].x;
        cc.x = zp[0].y; cc.y = zp[1].y; cc.z = zp[2].y; cc.w = zp[3].y;
        if (vb) {
            float4 vc = *(const float4*)(vb + p);
            float r0 = rsqrtf(fmaxf(vc.x, 1e-12f));
            float r1 = rsqrtf(fmaxf(vc.y, 1e-12f));
            float r2 = rsqrtf(fmaxf(vc.z, 1e-12f));
            float r3 = rsqrtf(fmaxf(vc.w, 1e-12f));
            a.x *= s0 * r0; a.y *= s0 * r1; a.z *= s0 * r2; a.w *= s0 * r3;
            cc.x *= s1 * r0; cc.y *= s1 * r1; cc.z *= s1 * r2; cc.w *= s1 * r3;
        } else {
            a.x *= s0; a.y *= s0; a.z *= s0; a.w *= s0;
            cc.x *= s1; cc.y *= s1; cc.z *= s1; cc.w *= s1;
        }
        *(float4*)(op + off0 + p) = a;
        *(float4*)(op + off1 + p) = cc;
    }
}

// wfft in the transform layout, via the SAME forward passes (layouts match).
// Also zeroes the var accumulator (replaces the hipMemsetAsync dispatch).
__global__ __launch_bounds__(256, 4)
void wfft_kernel(const float* __restrict__ w, float2* wfft_br,
                 float* __restrict__ var_zero)
{
    __shared__ float2 z[64 * CP];
    const int tid = threadIdx.x;
#pragma unroll
    for (int i = 0; i < 32; ++i) var_zero[tid + 256 * i] = 0.f;
    const int u   = ((tid >> 6) << 4) | (tid & 15);
    const int k1  = (tid >> 4) & 3;
    const float c1r = (k1 == 0) ? 1.f : ((k1 == 2) ? -1.f : 0.f);
    const float c1i = (k1 == 1) ? -1.f : ((k1 == 3) ? 1.f : 0.f);
    const float s2  = (k1 & 1) ? -1.f : 1.f;
    const float ang = -0.09817477042468103f * (float)k1;
    const float2 Wb = make_float2(cosf(ang), sinf(ang));

#pragma unroll
    for (int i = 0; i < 16; ++i) {
        int p = tid + 256 * i;
        z[(p >> 6) * CP + (p & 63)] = make_float2(w[p], 0.f);
    }
    __syncthreads();
    fwd_pass<CP, 1, false>(z, nullptr, u, k1, c1r, c1i, s2, Wb);
    fwd_pass<1, CP, false>(z, nullptr, u, k1, c1r, c1i, s2, Wb);
#pragma unroll
    for (int i = 0; i < 16; ++i) {
        int p = tid + 256 * i;
        wfft_br[p] = z[(p >> 6) * CP + (p & 63)];
    }
}

// In-place per-batch transpose of X1, TRIANGULAR grid (only by<=bx blocks
// launched; l -> (bx,by) decode). Batched float4 global I/O. FUSED diag
// (validated round 3): var[a] = sum_J w2d[a (-) J] * X1[J][a]; tile (by,bx)
// contributes, per local col c, a 64-tap circular correlation of tA[c][.]
// with weight row ((bx-by)&63). Partials via LDS reduce + 1 atomicAdd/col.
__global__ __launch_bounds__(256, 4)
void transpose_inplace_kernel(float* data, const float* __restrict__ weight,
                              float* __restrict__ var)
{
    const int l = blockIdx.x;            // 0..2079 triangular index
    int bx = (int)((sqrtf(8.f * (float)l + 1.f) - 1.f) * 0.5f);
    while ((bx + 1) * (bx + 2) / 2 <= l) ++bx;   // fp guard
    while (bx * (bx + 1) / 2 > l) --bx;
    const int by = l - bx * (bx + 1) / 2;
    const int b  = blockIdx.y;

    __shared__ float tA[64 * 65];
    __shared__ float tB[64 * 65];
    __shared__ float wAs[64], wBs[64];
    __shared__ float red[512];
    const int tid = threadIdx.x;
    const int f  = tid & 15;
    const int r0 = tid >> 4;
    long long base = (long long)b * NN * NN;
    float* A  = data + base + (long long)(by * 64) * NN + bx * 64;
    float* Bt = data + base + (long long)(bx * 64) * NN + by * 64;

    if (tid < 64)       wAs[tid]      = weight[(((bx - by) & 63) << 6) + tid];
    else if (tid < 128) wBs[tid - 64] = weight[(((by - bx) & 63) << 6) + (tid - 64)];

    const int c = tid & 63, q = tid >> 6;   // partial-dot assignment

    if (bx == by) {
        float4 va[4];
#pragma unroll
        for (int it = 0; it < 4; ++it) {
            int r = r0 + 16 * it;
            va[it] = *(const float4*)(A + (long long)r * NN + 4 * f);
        }
#pragma unroll
        for (int it = 0; it < 4; ++it) {
            int r = r0 + 16 * it;
            tA[(4 * f + 0) * 65 + r] = va[it].x; tA[(4 * f + 1) * 65 + r] = va[it].y;
            tA[(4 * f + 2) * 65 + r] = va[it].z; tA[(4 * f + 3) * 65 + r] = va[it].w;
        }
        __syncthreads();
        float4 ov[4];
#pragma unroll
        for (int it = 0; it < 4; ++it) {
            int cc = r0 + 16 * it;
            ov[it].x = tA[cc * 65 + 4 * f + 0]; ov[it].y = tA[cc * 65 + 4 * f + 1];
            ov[it].z = tA[cc * 65 + 4 * f + 2]; ov[it].w = tA[cc * 65 + 4 * f + 3];
        }
        float sA = 0.f;
#pragma unroll
        for (int k = 0; k < 16; ++k) {
            int r = q * 16 + k;
            sA = fmaf(wAs[(c - r) & 63], tA[c * 65 + r], sA);
        }
        red[tid] = sA;
        __syncthreads();
        if (tid < 64) {
            float v = red[tid] + red[tid + 64] + red[tid + 128] + red[tid + 192];
            atomicAdd(&var[(long long)b * NN + bx * 64 + tid], v);
        }
#pragma unroll
        for (int it = 0; it < 4; ++it) {
            int cc = r0 + 16 * it;
            *(float4*)(A + (long long)cc * NN + 4 * f) = ov[it];
        }
    } else {
        float4 va[4], wb[4];
#pragma unroll
        for (int it = 0; it < 4; ++it) {
            int r = r0 + 16 * it;
            va[it] = *(const float4*)(A  + (long long)r * NN + 4 * f);
            wb[it] = *(const float4*)(Bt + (long long)r * NN + 4 * f);
        }
#pragma unroll
        for (int it = 0; it < 4; ++it) {
            int r = r0 + 16 * it;
            tA[(4 * f + 0) * 65 + r] = va[it].x; tA[(4 * f + 1) * 65 + r] = va[it].y;
            tA[(4 * f + 2) * 65 + r] = va[it].z; tA[(4 * f + 3) * 65 + r] = va[it].w;
            tB[(4 * f + 0) * 65 + r] = wb[it].x; tB[(4 * f + 1) * 65 + r] = wb[it].y;
            tB[(4 * f + 2) * 65 + r] = wb[it].z; tB[(4 * f + 3) * 65 + r] = wb[it].w;
        }
        __syncthreads();
        float4 ov[4], ow[4];
#pragma unroll
        for (int it = 0; it < 4; ++it) {
            int cc = r0 + 16 * it;
            ov[it].x = tB[cc * 65 + 4 * f + 0]; ov[it].y = tB[cc * 65 + 4 * f + 1];
            ov[it].z = tB[cc * 65 + 4 * f + 2]; ov[it].w = tB[cc * 65 + 4 * f + 3];
            ow[it].x = tA[cc * 65 + 4 * f + 0]; ow[it].y = tA[cc * 65 + 4 * f + 1];
            ow[it].z = tA[cc * 65 + 4 * f + 2]; ow[it].w = tA[cc * 65 + 4 * f + 3];
        }
        float sA = 0.f, sB = 0.f;
#pragma unroll
        for (int k = 0; k < 16; ++k) {
            int r = q * 16 + k;
            sA = fmaf(wAs[(c - r) & 63], tA[c * 65 + r], sA);
            sB = fmaf(wBs[(c - r) & 63], tB[c * 65 + r], sB);
        }
        red[tid] = sA; red[256 + tid] = sB;
        __syncthreads();
        if (tid < 64) {
            float v = red[tid] + red[tid + 64] + red[tid + 128] + red[tid + 192];
            atomicAdd(&var[(long long)b * NN + bx * 64 + tid], v);
        } else if (tid < 128) {
            int t = tid - 64;
            float v = red[256 + t] + red[320 + t] + red[384 + t] + red[448 + t];
            atomicAdd(&var[(long long)b * NN + by * 64 + t], v);
        }
#pragma unroll
        for (int it = 0; it < 4; ++it) {
            int cc = r0 + 16 * it;
            *(float4*)(A  + (long long)cc * NN + 4 * f) = ov[it];
            *(float4*)(Bt + (long long)cc * NN + 4 * f) = ow[it];
        }
    }
}

extern "C" void kernel_launch(void* const* d_in, const int* in_sizes, int n_in,
                              void* d_out, int out_size, void* d_ws, size_t ws_size,
                              hipStream_t stream)
{
    const float* mean_in = (const float*)d_in[0];   // [2][64][64]
    const float* std_in  = (const float*)d_in[1];   // [2][64][64]
    const float* corr_in = (const float*)d_in[2];   // [2][4096][4096]
    const float* weight  = (const float*)d_in[3];   // [64][64]

    float* out      = (float*)d_out;
    float* mean_out = out;               // 8192
    float* std_out  = out + 8192;        // 8192
    float* corr_out = out + 16384;       // 2*4096*4096

    float*  ws      = (float*)d_ws;
    float2* wfft_br = (float2*)ws;       // 4096 float2 (8192 floats)
    float*  var_ws  = ws + 8192;         // 8192 floats

    // D1: wfft + var-accumulator zeroing
    wfft_kernel<<<1, 256, 0, stream>>>(weight, wfft_br, var_ws);

    // D2 (K1): conv along K for every row pair (s[I]*s[K] scaling) -> X1.
    // Last block handles the mean path.
    row_conv2_kernel<<<NB * NN / 2 + 1, 256, 0, stream>>>(
        corr_in, corr_out, wfft_br, std_in, nullptr, mean_in, mean_out, nullptr);

    // D3 (K2): in-place transpose -> X1^T, fused diag-of-cov (var), triangular grid
    transpose_inplace_kernel<<<dim3(2080, NB), 256, 0, stream>>>(corr_out, weight,
                                                                 var_ws);

    // D4 (K3): conv along I, in place, fused normalize (rstd inline via rsqrtf
    // from raw var). Last block writes std_out. Symmetry: no final transpose.
    row_conv2_kernel<<<NB * NN / 2 + 1, 256, 0, stream>>>(
        corr_out, corr_out, wfft_br, nullptr, var_ws, nullptr, nullptr, std_out);
}

// Round 9
// 420.407 us; speedup vs baseline: 1.0782x; 1.0782x over previous
//
#include <hip/hip_runtime.h>
#include <math.h>

#define DXY   64
#define NN    4096      // 64*64
#define NB    2
#define CP    65        // LDS complex pitch. Pitch-65 beats XOR-swizzle (R5 vs
                        // R7 K3 A/B: 113.5 vs 120 us): 2-way conflicts are free,
                        // swizzle address math is not.

#define C16 0.9238795325112867f
#define S16 0.3826834323650898f
#define R22 0.7071067811865476f

__device__ __forceinline__ void cmul_ip(float2& a, float wr, float wi) {
    float t = a.x * wr - a.y * wi;
    a.y = a.x * wi + a.y * wr;
    a.x = t;
}

// radix-4 core in place on y[i0..i3]; inv selects +i rotation (conj core, unscaled)
__device__ __forceinline__ void bf4(float2* y, int i0, int i1, int i2, int i3, int inv) {
    float2 a0 = y[i0], a1 = y[i1], a2 = y[i2], a3 = y[i3];
    float t0r = a0.x + a2.x, t0i = a0.y + a2.y;
    float t1r = a0.x - a2.x, t1i = a0.y - a2.y;
    float t2r = a1.x + a3.x, t2i = a1.y + a3.y;
    float dr  = a1.x - a3.x, di  = a1.y - a3.y;
    float t3r, t3i;
    if (inv) { t3r = -di; t3i = dr; } else { t3r = di; t3i = -dr; }
    y[i0] = make_float2(t0r + t2r, t0i + t2i);
    y[i1] = make_float2(t1r + t3r, t1i + t3i);
    y[i2] = make_float2(t0r - t2r, t0i - t2i);
    y[i3] = make_float2(t1r - t3r, t1i - t3i);
}

// 16-pt DIF radix-4 (natural in, base-4 digit-reversed out), constant twiddles
__device__ __forceinline__ void fft16_fwd(float2* y) {
    bf4(y, 0, 4, 8, 12, 0);
    bf4(y, 1, 5, 9, 13, 0);
    cmul_ip(y[5],  C16, -S16); cmul_ip(y[9],  R22, -R22); cmul_ip(y[13],  S16, -C16);
    bf4(y, 2, 6, 10, 14, 0);
    cmul_ip(y[6],  R22, -R22); cmul_ip(y[10], 0.f, -1.f); cmul_ip(y[14], -R22, -R22);
    bf4(y, 3, 7, 11, 15, 0);
    cmul_ip(y[7],  S16, -C16); cmul_ip(y[11], -R22, -R22); cmul_ip(y[15], -C16,  S16);
    bf4(y, 0, 1, 2, 3, 0); bf4(y, 4, 5, 6, 7, 0);
    bf4(y, 8, 9, 10, 11, 0); bf4(y, 12, 13, 14, 15, 0);
}

// exact unscaled inverse of fft16_fwd (consumes its layout), = 16 * IDFT16
__device__ __forceinline__ void fft16_inv(float2* y) {
    bf4(y, 0, 1, 2, 3, 1); bf4(y, 4, 5, 6, 7, 1);
    bf4(y, 8, 9, 10, 11, 1); bf4(y, 12, 13, 14, 15, 1);
    cmul_ip(y[5],  C16,  S16); cmul_ip(y[9],  R22,  R22); cmul_ip(y[13],  S16,  C16);
    cmul_ip(y[6],  R22,  R22); cmul_ip(y[10], 0.f,  1.f); cmul_ip(y[14], -R22,  R22);
    cmul_ip(y[7],  S16,  C16); cmul_ip(y[11], -R22,  R22); cmul_ip(y[15], -C16, -S16);
    bf4(y, 0, 4, 8, 12, 1); bf4(y, 1, 5, 9, 13, 1);
    bf4(y, 2, 6, 10, 14, 1); bf4(y, 3, 7, 11, 15, 1);
}

// Forward 64-pt FFT over 64 lines. Thread (u,k1): cross radix-4 gather (4-way
// broadcast reads) -> in-register 16-pt FFT -> [optional W-mult] -> write own
// segment [16k1..16k1+15]. US = line stride, NS = element stride (complex).
template<int US, int NS, bool FUSEW>
__device__ void fwd_pass(float2* z, const float2* __restrict__ wf, int u, int k1,
                         float c1r, float c1i, float s2, float2 Wb)
{
    const int B = u * US;
    float2 y[16];
    float twr = 1.f, twi = 0.f;
#pragma unroll
    for (int n2 = 0; n2 < 16; ++n2) {
        float2 x0 = z[B + n2 * NS];
        float2 x1 = z[B + (n2 + 16) * NS];
        float2 x2 = z[B + (n2 + 32) * NS];
        float2 x3 = z[B + (n2 + 48) * NS];
        float er  = fmaf(s2, x2.x, x0.x), ei = fmaf(s2, x2.y, x0.y);
        float orr = fmaf(s2, x3.x, x1.x), oi = fmaf(s2, x3.y, x1.y);
        float br = er + c1r * orr - c1i * oi;
        float bi = ei + c1r * oi + c1i * orr;
        y[n2].x = twr * br - twi * bi;
        y[n2].y = twr * bi + twi * br;
        float t = twr * Wb.x - twi * Wb.y;
        twi = twr * Wb.y + twi * Wb.x;
        twr = t;
    }
    fft16_fwd(y);
    if (FUSEW) {
#pragma unroll
        for (int p = 0; p < 16; ++p) {
            float2 wv = wf[(16 * k1 + p) * 64 + u];
            cmul_ip(y[p], wv.x, wv.y);
        }
    }
    __syncthreads();   // all gather reads complete before anyone overwrites
#pragma unroll
    for (int p = 0; p < 16; ++p) z[B + (16 * k1 + p) * NS] = y[p];
    __syncthreads();
}

// Inverse: read own segment -> in-register 16-pt IFFT -> conj cross twiddle ->
// store H -> gather across segments -> conj cross radix-4 -> write natural.
template<int US, int NS>
__device__ void inv_pass(float2* z, int u, int k1,
                         float ci1r, float ci1i, float s2, float2 Wbc)
{
    const int B = u * US;
    float2 y[16];
#pragma unroll
    for (int p = 0; p < 16; ++p) y[p] = z[B + (16 * k1 + p) * NS];
    fft16_inv(y);
    float twr = 1.f, twi = 0.f;
#pragma unroll
    for (int n2 = 0; n2 < 16; ++n2) {
        cmul_ip(y[n2], twr, twi);
        float t = twr * Wbc.x - twi * Wbc.y;
        twi = twr * Wbc.y + twi * Wbc.x;
        twr = t;
    }
#pragma unroll
    for (int n2 = 0; n2 < 16; ++n2) z[B + (16 * k1 + n2) * NS] = y[n2]; // own slots
    __syncthreads();
    float2 xx[16];
#pragma unroll
    for (int n2 = 0; n2 < 16; ++n2) {
        float2 h0 = z[B + n2 * NS];
        float2 h1 = z[B + (n2 + 16) * NS];
        float2 h2 = z[B + (n2 + 32) * NS];
        float2 h3 = z[B + (n2 + 48) * NS];
        float er  = fmaf(s2, h2.x, h0.x), ei = fmaf(s2, h2.y, h0.y);
        float orr = fmaf(s2, h3.x, h1.x), oi = fmaf(s2, h3.y, h1.y);
        xx[n2].x = er + ci1r * orr - ci1i * oi;
        xx[n2].y = ei + ci1r * oi + ci1i * orr;
    }
    __syncthreads();
#pragma unroll
    for (int n2 = 0; n2 < 16; ++n2) z[B + (16 * k1 + n2) * NS] = xx[n2];
    __syncthreads();
}

// Packed per-row-pair conv: rows (2blk, 2blk+1) -> re/im of one complex 64x64
// 2D FFT conv. Optional s[I]*s[K] input scaling (sstd); optional fused
// normalize (rstd): out[a][c] *= rstd[a]*rstd[c]. If mean_i != nullptr, the
// LAST block instead processes the mean path. Coalesced LDS epilogue:
// each wave store instruction covers a contiguous 1 KB.
__global__ __launch_bounds__(256, 4)
void row_conv2_kernel(const float* __restrict__ in, float* __restrict__ out,
                      const float2* __restrict__ wfft_br,
                      const float* __restrict__ sstd,
                      const float* __restrict__ rstd,
                      const float* __restrict__ mean_i,
                      float* __restrict__ mean_o)
{
    __shared__ float2 z[64 * CP];
    const int tid = threadIdx.x;
    const int u   = ((tid >> 6) << 4) | (tid & 15);
    const int k1  = (tid >> 4) & 3;
    const float c1r = (k1 == 0) ? 1.f : ((k1 == 2) ? -1.f : 0.f);
    const float c1i = (k1 == 1) ? -1.f : ((k1 == 3) ? 1.f : 0.f);
    const float s2  = (k1 & 1) ? -1.f : 1.f;
    const float ang = -0.09817477042468103f * (float)k1;   // -2π/64 * k1
    const float2 Wb  = make_float2(cosf(ang), sinf(ang));
    const float2 Wbc = make_float2(Wb.x, -Wb.y);
    const float ci1r = c1r, ci1i = -c1i;

    const float* ip = in;
    float*       op = out;
    const float* sstdp = sstd;
    const float* rstdp = rstd;
    int bid = blockIdx.x;
    if (mean_i && bid == (int)gridDim.x - 1) {
        ip = mean_i; op = mean_o; sstdp = nullptr; rstdp = nullptr; bid = 0;
    }

    const int row0 = 2 * bid;
    const long long off0 = (long long)row0 * NN, off1 = off0 + NN;
    const int b   = row0 >> 12;
    const int rI0 = row0 & (NN - 1), rI1 = rI0 + 1;
    const float* sb = nullptr;
    float sI0 = 1.f, sI1 = 1.f;
    if (sstdp) { sb = sstdp + (long long)b * NN; sI0 = sb[rI0]; sI1 = sb[rI1]; }

    // batched loads: all global reads in flight before any LDS write
    float4 a4[4], c4[4], s4[4];
#pragma unroll
    for (int i = 0; i < 4; ++i) {
        int p = (tid + 256 * i) * 4;
        a4[i] = *(const float4*)(ip + off0 + p);
        c4[i] = *(const float4*)(ip + off1 + p);
    }
    if (sb) {
#pragma unroll
        for (int i = 0; i < 4; ++i) {
            int p = (tid + 256 * i) * 4;
            s4[i] = *(const float4*)(sb + p);
        }
    }
#pragma unroll
    for (int i = 0; i < 4; ++i) {
        int p = (tid + 256 * i) * 4;
        int r = p >> 6, c = p & 63;
        float4 a = a4[i], cc = c4[i];
        if (sb) {
            float4 s = s4[i];
            a.x *= sI0 * s.x; a.y *= sI0 * s.y; a.z *= sI0 * s.z; a.w *= sI0 * s.w;
            cc.x *= sI1 * s.x; cc.y *= sI1 * s.y; cc.z *= sI1 * s.z; cc.w *= sI1 * s.w;
        }
        float2* zp = z + r * CP + c;
        zp[0] = make_float2(a.x, cc.x);
        zp[1] = make_float2(a.y, cc.y);
        zp[2] = make_float2(a.z, cc.z);
        zp[3] = make_float2(a.w, cc.w);
    }
    __syncthreads();

    fwd_pass<CP, 1, false>(z, nullptr,  u, k1, c1r, c1i, s2, Wb);  // fast axis
    fwd_pass<1, CP, true >(z, wfft_br,  u, k1, c1r, c1i, s2, Wb);  // slow axis + W
    inv_pass<1, CP>(z, u, k1, ci1r, ci1i, s2, Wbc);                // slow axis
    inv_pass<CP, 1>(z, u, k1, ci1r, ci1i, s2, Wbc);                // fast axis

    const float scale = 1.0f / 4096.0f;
    float s0 = scale, s1 = scale;
    const float* rsb = nullptr;
    if (rstdp) {
        rsb = rstdp + (long long)b * NN;
        s0 *= rsb[rI0];
        s1 *= rsb[rI1];
    }
#pragma unroll
    for (int i = 0; i < 4; ++i) {
        int idx = tid + 256 * i;
        int p = idx * 4;
        int r = p >> 6, c = p & 63;
        const float2* zp = z + r * CP + c;
        float4 a, cc;
        a.x = zp[0].x; a.y = zp[1].x; a.z = zp[2].x; a.w = zp[3].x;
        cc.x = zp[0].y; cc.y = zp[1].y; cc.z = zp[2].y; cc.w = zp[3].y;
        if (rsb) {
            float4 rc = *(const float4*)(rsb + p);
            a.x *= s0 * rc.x; a.y *= s0 * rc.y; a.z *= s0 * rc.z; a.w *= s0 * rc.w;
            cc.x *= s1 * rc.x; cc.y *= s1 * rc.y; cc.z *= s1 * rc.z; cc.w *= s1 * rc.w;
        } else {
            a.x *= s0; a.y *= s0; a.z *= s0; a.w *= s0;
            cc.x *= s1; cc.y *= s1; cc.z *= s1; cc.w *= s1;
        }
        *(float4*)(op + off0 + p) = a;
        *(float4*)(op + off1 + p) = cc;
    }
}

// wfft in the transform layout, via the SAME forward passes (layouts match).
// Also zeroes the var accumulator (replaces the hipMemsetAsync dispatch).
__global__ __launch_bounds__(256, 4)
void wfft_kernel(const float* __restrict__ w, float2* wfft_br,
                 float* __restrict__ var_zero)
{
    __shared__ float2 z[64 * CP];
    const int tid = threadIdx.x;
#pragma unroll
    for (int i = 0; i < 32; ++i) var_zero[tid + 256 * i] = 0.f;
    const int u   = ((tid >> 6) << 4) | (tid & 15);
    const int k1  = (tid >> 4) & 3;
    const float c1r = (k1 == 0) ? 1.f : ((k1 == 2) ? -1.f : 0.f);
    const float c1i = (k1 == 1) ? -1.f : ((k1 == 3) ? 1.f : 0.f);
    const float s2  = (k1 & 1) ? -1.f : 1.f;
    const float ang = -0.09817477042468103f * (float)k1;
    const float2 Wb = make_float2(cosf(ang), sinf(ang));

#pragma unroll
    for (int i = 0; i < 16; ++i) {
        int p = tid + 256 * i;
        z[(p >> 6) * CP + (p & 63)] = make_float2(w[p], 0.f);
    }
    __syncthreads();
    fwd_pass<CP, 1, false>(z, nullptr, u, k1, c1r, c1i, s2, Wb);
    fwd_pass<1, CP, false>(z, nullptr, u, k1, c1r, c1i, s2, Wb);
#pragma unroll
    for (int i = 0; i < 16; ++i) {
        int p = tid + 256 * i;
        wfft_br[p] = z[(p >> 6) * CP + (p & 63)];
    }
}

// In-place per-batch transpose of X1, TRIANGULAR grid (only by<=bx launched,
// l -> (bx,by) decode). Batched float4 global I/O. FUSED diag (validated
// round 3): var[a] = sum_J w2d[a (-) J] * X1[J][a]; tile (by,bx) contributes,
// per local col c, a 64-tap circular correlation of tA[c][.] with weight row
// ((bx-by)&63). Partials via LDS reduce + 1 atomicAdd/col.
__global__ __launch_bounds__(256, 4)
void transpose_inplace_kernel(float* data, const float* __restrict__ weight,
                              float* __restrict__ var)
{
    const int l = blockIdx.x;            // 0..2079 triangular index
    int bx = (int)((sqrtf(8.f * (float)l + 1.f) - 1.f) * 0.5f);
    while ((bx + 1) * (bx + 2) / 2 <= l) ++bx;   // fp guard
    while (bx * (bx + 1) / 2 > l) --bx;
    const int by = l - bx * (bx + 1) / 2;
    const int b  = blockIdx.y;

    __shared__ float tA[64 * 65];
    __shared__ float tB[64 * 65];
    __shared__ float wAs[64], wBs[64];
    __shared__ float red[512];
    const int tid = threadIdx.x;
    const int f  = tid & 15;
    const int r0 = tid >> 4;
    long long base = (long long)b * NN * NN;
    float* A  = data + base + (long long)(by * 64) * NN + bx * 64;
    float* Bt = data + base + (long long)(bx * 64) * NN + by * 64;

    if (tid < 64)       wAs[tid]      = weight[(((bx - by) & 63) << 6) + tid];
    else if (tid < 128) wBs[tid - 64] = weight[(((by - bx) & 63) << 6) + (tid - 64)];

    const int c = tid & 63, q = tid >> 6;   // partial-dot assignment

    if (bx == by) {
        float4 va[4];
#pragma unroll
        for (int it = 0; it < 4; ++it) {
            int r = r0 + 16 * it;
            va[it] = *(const float4*)(A + (long long)r * NN + 4 * f);
        }
#pragma unroll
        for (int it = 0; it < 4; ++it) {
            int r = r0 + 16 * it;
            tA[(4 * f + 0) * 65 + r] = va[it].x; tA[(4 * f + 1) * 65 + r] = va[it].y;
            tA[(4 * f + 2) * 65 + r] = va[it].z; tA[(4 * f + 3) * 65 + r] = va[it].w;
        }
        __syncthreads();
        float4 ov[4];
#pragma unroll
        for (int it = 0; it < 4; ++it) {
            int cc = r0 + 16 * it;
            ov[it].x = tA[cc * 65 + 4 * f + 0]; ov[it].y = tA[cc * 65 + 4 * f + 1];
            ov[it].z = tA[cc * 65 + 4 * f + 2]; ov[it].w = tA[cc * 65 + 4 * f + 3];
        }
        float sA = 0.f;
#pragma unroll
        for (int k = 0; k < 16; ++k) {
            int r = q * 16 + k;
            sA = fmaf(wAs[(c - r) & 63], tA[c * 65 + r], sA);
        }
        red[tid] = sA;
        __syncthreads();
        if (tid < 64) {
            float v = red[tid] + red[tid + 64] + red[tid + 128] + red[tid + 192];
            atomicAdd(&var[(long long)b * NN + bx * 64 + tid], v);
        }
#pragma unroll
        for (int it = 0; it < 4; ++it) {
            int cc = r0 + 16 * it;
            *(float4*)(A + (long long)cc * NN + 4 * f) = ov[it];
        }
    } else {
        float4 va[4], wb[4];
#pragma unroll
        for (int it = 0; it < 4; ++it) {
            int r = r0 + 16 * it;
            va[it] = *(const float4*)(A  + (long long)r * NN + 4 * f);
            wb[it] = *(const float4*)(Bt + (long long)r * NN + 4 * f);
        }
#pragma unroll
        for (int it = 0; it < 4; ++it) {
            int r = r0 + 16 * it;
            tA[(4 * f + 0) * 65 + r] = va[it].x; tA[(4 * f + 1) * 65 + r] = va[it].y;
            tA[(4 * f + 2) * 65 + r] = va[it].z; tA[(4 * f + 3) * 65 + r] = va[it].w;
            tB[(4 * f + 0) * 65 + r] = wb[it].x; tB[(4 * f + 1) * 65 + r] = wb[it].y;
            tB[(4 * f + 2) * 65 + r] = wb[it].z; tB[(4 * f + 3) * 65 + r] = wb[it].w;
        }
        __syncthreads();
        float4 ov[4], ow[4];
#pragma unroll
        for (int it = 0; it < 4; ++it) {
            int cc = r0 + 16 * it;
            ov[it].x = tB[cc * 65 + 4 * f + 0]; ov[it].y = tB[cc * 65 + 4 * f + 1];
            ov[it].z = tB[cc * 65 + 4 * f + 2]; ov[it].w = tB[cc * 65 + 4 * f + 3];
            ow[it].x = tA[cc * 65 + 4 * f + 0]; ow[it].y = tA[cc * 65 + 4 * f + 1];
            ow[it].z = tA[cc * 65 + 4 * f + 2]; ow[it].w = tA[cc * 65 + 4 * f + 3];
        }
        float sA = 0.f, sB = 0.f;
#pragma unroll
        for (int k = 0; k < 16; ++k) {
            int r = q * 16 + k;
            sA = fmaf(wAs[(c - r) & 63], tA[c * 65 + r], sA);
            sB = fmaf(wBs[(c - r) & 63], tB[c * 65 + r], sB);
        }
        red[tid] = sA; red[256 + tid] = sB;
        __syncthreads();
        if (tid < 64) {
            float v = red[tid] + red[tid + 64] + red[tid + 128] + red[tid + 192];
            atomicAdd(&var[(long long)b * NN + bx * 64 + tid], v);
        } else if (tid < 128) {
            int t = tid - 64;
            float v = red[256 + t] + red[320 + t] + red[384 + t] + red[448 + t];
            atomicAdd(&var[(long long)b * NN + by * 64 + t], v);
        }
#pragma unroll
        for (int it = 0; it < 4; ++it) {
            int cc = r0 + 16 * it;
            *(float4*)(A  + (long long)cc * NN + 4 * f) = ov[it];
            *(float4*)(Bt + (long long)cc * NN + 4 * f) = ow[it];
        }
    }
}

__global__ __launch_bounds__(256)
void std_kernel(const float* __restrict__ var, float* std_out, float* rstd, int n)
{
    int i = blockIdx.x * 256 + threadIdx.x;
    if (i < n) {
        float s = sqrtf(fmaxf(var[i], 1e-12f));
        std_out[i] = s;
        rstd[i] = 1.0f / s;
    }
}

extern "C" void kernel_launch(void* const* d_in, const int* in_sizes, int n_in,
                              void* d_out, int out_size, void* d_ws, size_t ws_size,
                              hipStream_t stream)
{
    const float* mean_in = (const float*)d_in[0];   // [2][64][64]
    const float* std_in  = (const float*)d_in[1];   // [2][64][64]
    const float* corr_in = (const float*)d_in[2];   // [2][4096][4096]
    const float* weight  = (const float*)d_in[3];   // [64][64]

    float* out      = (float*)d_out;
    float* mean_out = out;               // 8192
    float* std_out  = out + 8192;        // 8192
    float* corr_out = out + 16384;       // 2*4096*4096

    float*  ws      = (float*)d_ws;
    float2* wfft_br = (float2*)ws;       // 4096 float2 (8192 floats)
    float*  var_ws  = ws + 8192;         // 8192 floats
    float*  rstd_ws = ws + 16384;        // 8192 floats

    // D1: wfft + var-accumulator zeroing
    wfft_kernel<<<1, 256, 0, stream>>>(weight, wfft_br, var_ws);

    // D2 (K1): conv along K for every row pair (s[I]*s[K] scaling) -> X1.
    // Last block handles the mean path.
    row_conv2_kernel<<<NB * NN / 2 + 1, 256, 0, stream>>>(
        corr_in, corr_out, wfft_br, std_in, nullptr, mean_in, mean_out);

    // D3 (K2): in-place transpose -> X1^T, fused diag-of-cov (var), triangular grid
    transpose_inplace_kernel<<<dim3(2080, NB), 256, 0, stream>>>(corr_out, weight,
                                                                 var_ws);

    // D4: std/rstd from the diagonal (proven-fast plumbing; rstd broadcast to K3)
    std_kernel<<<(NB * NN + 255) / 256, 256, 0, stream>>>(var_ws, std_out,
                                                          rstd_ws, NB * NN);

    // D5 (K3): conv along I, in place, fused normalize via rstd_ws.
    // Symmetry: no final transpose.
    row_conv2_kernel<<<NB * NN / 2, 256, 0, stream>>>(
        corr_out, corr_out, wfft_br, nullptr, rstd_ws, nullptr, nullptr);
}